// Round 9
// baseline (78.709 us; speedup 1.0000x reference)
//
#include <hip/hip_runtime.h>
#include <cmath>

// JPEG layer, fully fused, persistent-wave software-prefetch pipeline.
// 2048 waves; each handles 4 "units" (unit = 4 horizontal 16x16 tiles) at the
// same (trow,tcq) across images {i, i+8, i+16, i+24} (constant ptr stride).
// Per iteration: consume prefetched pixel registers -> issue next unit's 12
// float4 loads -> sched_barrier pins them -> ~2500-instr codec block hides
// the latency. Lane (g=lane>>3, p=lane&7) owns row p of block-slot g.
// Butterfly 8-pt DCT/IDCT in-lane + DPP in-register 8x8 transposes.
// Quantizer round() decisions are f64-faithful via rare cold rescue.

#define LEVELD 0.5019607843137255
#define LEVELF 0.5019607843137255f
#define BAND   5.0e-5f

#define CA  0.35355339059327373f
#define CB0 0.49039264020161522f
#define CB1 0.41573480615127262f
#define CB2 0.27778511650980114f
#define CB3 0.09754516100806413f
#define CC0 0.46193976625564337f
#define CC1 0.19134171618254489f

__device__ const double DMATD[64] = {
  0.3535533905932738,  0.3535533905932738,  0.3535533905932738,  0.3535533905932738,
  0.3535533905932738,  0.3535533905932738,  0.3535533905932738,  0.3535533905932738,
  0.4903926402016152,  0.4157348061512726,  0.2777851165098011,  0.0975451610080641,
 -0.0975451610080641, -0.2777851165098011, -0.4157348061512726, -0.4903926402016152,
  0.4619397662556434,  0.1913417161825449, -0.1913417161825449, -0.4619397662556434,
 -0.4619397662556434, -0.1913417161825449,  0.1913417161825449,  0.4619397662556434,
  0.4157348061512726, -0.0975451610080641, -0.4903926402016152, -0.2777851165098011,
  0.2777851165098011,  0.4903926402016152,  0.0975451610080641, -0.4157348061512726,
  0.3535533905932738, -0.3535533905932738, -0.3535533905932738,  0.3535533905932738,
  0.3535533905932738, -0.3535533905932738, -0.3535533905932738,  0.3535533905932738,
  0.2777851165098011, -0.4903926402016152,  0.0975451610080641,  0.4157348061512726,
 -0.4157348061512726, -0.0975451610080641,  0.4903926402016152, -0.2777851165098011,
  0.1913417161825449, -0.4619397662556434,  0.4619397662556434, -0.1913417161825449,
 -0.1913417161825449,  0.4619397662556434, -0.4619397662556434,  0.1913417161825449,
  0.0975451610080641, -0.2777851165098011,  0.4157348061512726, -0.4903926402016152,
  0.4903926402016152, -0.4157348061512726,  0.2777851165098011, -0.0975451610080641
};

// ---- DPP cross-lane helpers (VALU only) ----
__device__ __forceinline__ float dpp_xor1(float x) {  // quad_perm(1,0,3,2)
  return __int_as_float(__builtin_amdgcn_mov_dpp(__float_as_int(x), 0xB1, 0xF, 0xF, true));
}
__device__ __forceinline__ float dpp_xor2(float x) {  // quad_perm(2,3,0,1)
  return __int_as_float(__builtin_amdgcn_mov_dpp(__float_as_int(x), 0x4E, 0xF, 0xF, true));
}
__device__ __forceinline__ float dpp_xor4(float x) {  // half_mirror o quad_mirror
  int t = __builtin_amdgcn_mov_dpp(__float_as_int(x), 0x141, 0xF, 0xF, true);
  return __int_as_float(__builtin_amdgcn_mov_dpp(t, 0x1B, 0xF, 0xF, true));
}

// in-register 8x8 transpose across the 8 lanes of a group; v[j]@p -> v[p]@j
__device__ __forceinline__ void transpose8(float v[8], int p) {
  { float t[8];
    #pragma unroll
    for (int j = 0; j < 8; ++j) t[j] = dpp_xor1(v[j ^ 1]);
    const bool lb = (p & 1) != 0;
    #pragma unroll
    for (int j = 0; j < 8; ++j) v[j] = (lb == ((j & 1) != 0)) ? v[j] : t[j];
  }
  { float t[8];
    #pragma unroll
    for (int j = 0; j < 8; ++j) t[j] = dpp_xor2(v[j ^ 2]);
    const bool lb = (p & 2) != 0;
    #pragma unroll
    for (int j = 0; j < 8; ++j) v[j] = (lb == ((j & 2) != 0)) ? v[j] : t[j];
  }
  { float t[8];
    #pragma unroll
    for (int j = 0; j < 8; ++j) t[j] = dpp_xor4(v[j ^ 4]);
    const bool lb = (p & 4) != 0;
    #pragma unroll
    for (int j = 0; j < 8; ++j) v[j] = (lb == ((j & 4) != 0)) ? v[j] : t[j];
  }
}

// forward 8-pt DCT (y = D x), butterflied
__device__ __forceinline__ void fdct8b(float x[8]) {
  const float s0 = x[0] + x[7], s1 = x[1] + x[6], s2 = x[2] + x[5], s3 = x[3] + x[4];
  const float d0 = x[0] - x[7], d1 = x[1] - x[6], d2 = x[2] - x[5], d3 = x[3] - x[4];
  const float t0 = s0 + s3, t1 = s1 + s2, t2 = s0 - s3, t3 = s1 - s2;
  x[0] = CA * (t0 + t1);
  x[4] = CA * (t0 - t1);
  x[2] = fmaf(CC0, t2,  CC1 * t3);
  x[6] = fmaf(CC1, t2, -CC0 * t3);
  x[1] = fmaf(CB0, d0, fmaf( CB1, d1, fmaf( CB2, d2,  CB3 * d3)));
  x[3] = fmaf(CB1, d0, fmaf(-CB3, d1, fmaf(-CB0, d2, -CB2 * d3)));
  x[5] = fmaf(CB2, d0, fmaf(-CB0, d1, fmaf( CB3, d2,  CB1 * d3)));
  x[7] = fmaf(CB3, d0, fmaf(-CB2, d1, fmaf( CB1, d2, -CB0 * d3)));
}
// inverse 8-pt DCT (o = D^T y), butterflied
__device__ __forceinline__ void idct8b(float y[8]) {
  const float pe = CA * (y[0] + y[4]), qe = CA * (y[0] - y[4]);
  const float re = fmaf(CC0, y[2],  CC1 * y[6]);
  const float se = fmaf(CC1, y[2], -CC0 * y[6]);
  const float E0 = pe + re, E3 = pe - re, E1 = qe + se, E2 = qe - se;
  const float O0 = fmaf(CB0, y[1], fmaf( CB1, y[3], fmaf( CB2, y[5],  CB3 * y[7])));
  const float O1 = fmaf(CB1, y[1], fmaf(-CB3, y[3], fmaf(-CB0, y[5], -CB2 * y[7])));
  const float O2 = fmaf(CB2, y[1], fmaf(-CB0, y[3], fmaf( CB3, y[5],  CB1 * y[7])));
  const float O3 = fmaf(CB3, y[1], fmaf(-CB2, y[3], fmaf( CB1, y[5], -CB0 * y[7])));
  y[0] = E0 + O0; y[7] = E0 - O0;
  y[1] = E1 + O1; y[6] = E1 - O1;
  y[2] = E2 + O2; y[5] = E2 - O2;
  y[3] = E3 + O3; y[4] = E3 - O3;
}

// f64 recompute of dequantized coefficient (i,j). mode 0 = Y (base = 8x8
// block base), mode 1 = Cb, mode 2 = Cr (base = 16x16 tile base). Cold.
__device__ __attribute__((noinline)) float rescue_coef(
    const float* __restrict__ quant, const float* __restrict__ base,
    int mode, int i, int j)
{
  double acc = 0.0;
  if (mode == 0) {
    #pragma unroll 1
    for (int k = 0; k < 8; ++k) {
      double e = 0.0;
      #pragma unroll
      for (int l = 0; l < 8; ++l) {
        const size_t off = (size_t)k * 512 + l;
        const double rr = (double)base[off];
        const double gg = (double)base[262144 + off];
        const double bb = (double)base[524288 + off];
        double y = 0.299 * rr + 0.587 * gg + 0.114 * bb;
        y = fmin(fmax(y, 0.0), 1.0) - LEVELD;
        e += y * DMATD[j * 8 + l];
      }
      acc += DMATD[i * 8 + k] * e;
    }
  } else {
    const double c0 = (mode == 1) ? -0.168735892 : 0.5;
    const double c1 = (mode == 1) ? -0.331264108 : -0.418687589;
    const double c2 = (mode == 1) ?  0.5         : -0.081312411;
    #pragma unroll 1
    for (int k = 0; k < 8; ++k) {
      double e = 0.0;
      #pragma unroll 1
      for (int l = 0; l < 8; ++l) {
        double m = 0.0;
        #pragma unroll
        for (int dr = 0; dr < 2; ++dr)
          #pragma unroll
          for (int dc = 0; dc < 2; ++dc) {
            const size_t off = (size_t)(2 * k + dr) * 512 + (2 * l + dc);
            const double rr = (double)base[off];
            const double gg = (double)base[262144 + off];
            const double bb = (double)base[524288 + off];
            const double v = c0 * rr + c1 * gg + c2 * bb;
            m += fmin(fmax(v + LEVELD, 0.0), 1.0) - LEVELD;
          }
        e += (0.25 * m) * DMATD[j * 8 + l];
      }
      acc += DMATD[i * 8 + k] * e;
    }
  }
  const double qd = rint((double)quant[i * 8 + j] * 255.0) * (1.0 / 255.0);
  return (float)(rint(acc / qd) * qd);
}

// per-block codec: DCT -> quant(round; deferred f64 rescue) -> IDCT, in place
__device__ __forceinline__ void codec8(float x[8], const float qv[8], const float rq[8],
                                       int p, int mode, const float* __restrict__ base,
                                       const float* __restrict__ quant)
{
  fdct8b(x); transpose8(x, p); fdct8b(x);
  unsigned bad = 0u;
  #pragma unroll
  for (int i = 0; i < 8; ++i) {
    const float tt = x[i] * rq[i];
    const float rt = rintf(tt);
    if (fabsf(tt - rt) > 0.5f - BAND) bad |= (1u << i);
    x[i] = rt * qv[i];
  }
  if (__builtin_expect(bad != 0u, 0)) {     // cold, branched-over patch
    do {
      const int i = __builtin_ctz(bad);
      bad &= bad - 1u;
      const float fix = rescue_coef(quant, base, mode, i, p);
      #pragma unroll
      for (int k = 0; k < 8; ++k) x[k] = (k == i) ? fix : x[k];
    } while (bad != 0u);
  }
  idct8b(x); transpose8(x, p); idct8b(x);
}

// issue the 12 float4 pixel loads of one unit into P[12]
__device__ __forceinline__ void load_unit(const float* __restrict__ tb,
                                          size_t lanerow, float4 P[12])
{
  #pragma unroll
  for (int h = 0; h < 2; ++h) {
    const float* pb = tb + lanerow + h * 32;   // tY = 2h+tx
    P[6 * h + 0] = *(const float4*)(pb);
    P[6 * h + 1] = *(const float4*)(pb + 4);
    P[6 * h + 2] = *(const float4*)(pb + 262144);
    P[6 * h + 3] = *(const float4*)(pb + 262148);
    P[6 * h + 4] = *(const float4*)(pb + 524288);
    P[6 * h + 5] = *(const float4*)(pb + 524292);
  }
}

// color + chroma-mean staging for one Y round (data already in registers)
__device__ __forceinline__ void color_stage(
    const float4* __restrict__ L6, int tY, int qr, int qc, int p,
    float4* __restrict__ CHW, float rout[8])
{
  const float RL[8] = {L6[0].x, L6[0].y, L6[0].z, L6[0].w, L6[1].x, L6[1].y, L6[1].z, L6[1].w};
  const float GL[8] = {L6[2].x, L6[2].y, L6[2].z, L6[2].w, L6[3].x, L6[3].y, L6[3].z, L6[3].w};
  const float BL[8] = {L6[4].x, L6[4].y, L6[4].z, L6[4].w, L6[5].x, L6[5].y, L6[5].z, L6[5].w};

  float cbv[8], crv[8];
  #pragma unroll
  for (int l = 0; l < 8; ++l) {
    const float rr = RL[l], gg = GL[l], bb = BL[l];
    const float y  = fmaf(0.114f, bb, fmaf(0.587f, gg, 0.299f * rr));
    const float cb = fmaf(0.5f, bb, fmaf(-0.331264108f, gg, -0.168735892f * rr));
    const float cr = fmaf(-0.081312411f, bb, fmaf(-0.418687589f, gg, 0.5f * rr));
    rout[l] = fminf(fmaxf(y,           0.0f), 1.0f) - LEVELF;
    cbv[l]  = fminf(fmaxf(cb + LEVELF, 0.0f), 1.0f) - LEVELF;
    crv[l]  = fminf(fmaxf(cr + LEVELF, 0.0f), 1.0f) - LEVELF;
  }
  float ch[4];
  #pragma unroll
  for (int j = 0; j < 4; ++j) {
    const float cbh = cbv[2 * j] + cbv[2 * j + 1];
    const float crh = crv[2 * j] + crv[2 * j + 1];
    const float cbs = cbh + dpp_xor1(cbh);
    const float crs = crh + dpp_xor1(crh);
    ch[j] = 0.25f * ((p & 1) ? crs : cbs);   // even lanes: cb, odd: cr
  }
  const int crow = qr * 4 + (p >> 1);
  const int slot = ((((p & 1) * 4 + tY) * 16) + crow * 2 + qc) ^ ((tY << 1) | qr);
  CHW[slot] = make_float4(ch[0], ch[1], ch[2], ch[3]);
}

// upsample chroma from LDS, YCC->RGB, clamp, store one Y round
__device__ __forceinline__ void out_phase(
    float* __restrict__ ob, int tY, int qr, int qc, int p,
    const float4* __restrict__ CHW, const float r[8])
{
  const int crow = qr * 4 + (p >> 1);
  const int swz = (tY << 1) | qr;
  const float4 cb4 = CHW[((tY * 16) + crow * 2 + qc) ^ swz];
  const float4 cr4 = CHW[(((4 + tY) * 16) + crow * 2 + qc) ^ swz];
  const float cba[4] = {cb4.x, cb4.y, cb4.z, cb4.w};
  const float cra[4] = {cr4.x, cr4.y, cr4.z, cr4.w};

  float RR[8], GG[8], BB[8];
  #pragma unroll
  for (int l = 0; l < 8; ++l) {
    const float y2 = r[l] + LEVELF;          // chroma LEVEL offsets cancel
    const float cbb = cba[l >> 1], crr = cra[l >> 1];
    float ro = fmaf(1.402f, crr, y2);
    float go = y2 - 0.344136286f * cbb - 0.714136286f * crr;
    float bo = fmaf(1.772f, cbb, y2);
    RR[l] = fminf(fmaxf(ro, 0.0f), 1.0f);
    GG[l] = fminf(fmaxf(go, 0.0f), 1.0f);
    BB[l] = fminf(fmaxf(bo, 0.0f), 1.0f);
  }
  float* op = ob + (size_t)(qr * 8 + p) * 512 + tY * 16 + qc * 8;
  *(float4*)(op)              = make_float4(RR[0], RR[1], RR[2], RR[3]);
  *(float4*)(op + 4)          = make_float4(RR[4], RR[5], RR[6], RR[7]);
  *(float4*)(op + 262144)     = make_float4(GG[0], GG[1], GG[2], GG[3]);
  *(float4*)(op + 262148)     = make_float4(GG[4], GG[5], GG[6], GG[7]);
  *(float4*)(op + 524288)     = make_float4(BB[0], BB[1], BB[2], BB[3]);
  *(float4*)(op + 524292)     = make_float4(BB[4], BB[5], BB[6], BB[7]);
}

#define UNIT_STRIDE 6291456   // 8 images * 786432 floats

__global__ __launch_bounds__(256, 2) void jpeg_fused(
    const float* __restrict__ in, const float* __restrict__ quant,
    float* __restrict__ out)
{
  __shared__ float4 CH[4][128];   // per wave: 8 chroma blocks (swizzled), 2 KiB

  const int wv   = threadIdx.x >> 6;
  const int lane = threadIdx.x & 63;
  const int g = lane >> 3, p = lane & 7;
  const int tx = g >> 2, qr = (g >> 1) & 1, qc = g & 1;

  // wave 0..2047: images {img0, img0+8, img0+16, img0+24} at (trow, tcq)
  const int wave_id = blockIdx.x * 4 + wv;
  const int img0 = wave_id >> 8;
  const int trow = (wave_id >> 3) & 31;
  const int tcq  = wave_id & 7;
  const size_t base0 = (size_t)img0 * 786432 + (size_t)trow * 8192 + (size_t)tcq * 64;
  float4* CHW = &CH[wv][0];

  // per-lane offset of Y-row within a unit (tile-half h adds +32)
  const size_t lanerow = (size_t)(qr * 8 + p) * 512 + tx * 16 + qc * 8;

  // quantizer column p in f32: rintf(q*255) exact for q*255 in [40,50];
  // <=1-ulp dequant diff vs f64, arbitrated by the f64 rescue anyway
  float qv[8], rq[8];
  #pragma unroll
  for (int i = 0; i < 8; ++i) {
    qv[i] = rintf(quant[i * 8 + p] * 255.0f) * (1.0f / 255.0f);
    rq[i] = 1.0f / qv[i];
  }

  float4 P[12];
  load_unit(in + base0, lanerow, P);          // prologue prefetch (unit 0)

  #pragma unroll 1
  for (int k = 0; k < 4; ++k) {
    const float* tb_cur = in + base0 + (size_t)k * UNIT_STRIDE;
    float* ob = out + base0 + (size_t)k * UNIT_STRIDE;

    // consume prefetched registers (the only vmcnt wait per iteration)
    float rA[8], rB[8];
    color_stage(&P[0], 0 + tx, qr, qc, p, CHW, rA);
    color_stage(&P[6], 2 + tx, qr, qc, p, CHW, rB);
    __builtin_amdgcn_wave_barrier();

    // issue next unit's loads now; pin them above the codec block
    if (k < 3) load_unit(tb_cur + UNIT_STRIDE, lanerow, P);
    __builtin_amdgcn_sched_barrier(0);

    // ---- Y codecs (call-free fast path) ----
    const float* blkA = tb_cur + (size_t)qr * 4096 + (0 + tx) * 16 + qc * 8;
    const float* blkB = tb_cur + (size_t)qr * 4096 + (2 + tx) * 16 + qc * 8;
    codec8(rA, qv, rq, p, 0, blkA, quant);
    codec8(rB, qv, rq, p, 0, blkB, quant);

    // ---- chroma codec: 8 blocks (g>>2: 0=Cb,1=Cr; g&3: unit tile) ----
    {
      const int cpar = g >> 2, ct = g & 3;
      const int pre  = (cpar * 4 + ct) * 16 + p * 2;
      const int swz  = (ct << 1) | (p >> 2);
      const int sl = pre ^ swz, sh = (pre + 1) ^ swz;
      const float4 a = CHW[sl];
      const float4 b = CHW[sh];
      float xc[8] = {a.x, a.y, a.z, a.w, b.x, b.y, b.z, b.w};
      codec8(xc, qv, rq, p, 1 + cpar, tb_cur + ct * 16, quant);
      CHW[sl] = make_float4(xc[0], xc[1], xc[2], xc[3]);
      CHW[sh] = make_float4(xc[4], xc[5], xc[6], xc[7]);
    }
    __builtin_amdgcn_wave_barrier();

    // ---- output both rounds ----
    out_phase(ob, 0 + tx, qr, qc, p, CHW, rA);
    out_phase(ob, 2 + tx, qr, qc, p, CHW, rB);
    __builtin_amdgcn_wave_barrier();
  }
}

extern "C" void kernel_launch(void* const* d_in, const int* in_sizes, int n_in,
                              void* d_out, int out_size, void* d_ws, size_t ws_size,
                              hipStream_t stream) {
  const float* in    = (const float*)d_in[0];
  const float* quant = (const float*)d_in[1];  // only quantize[0] (64 floats) used
  float* out = (float*)d_out;

  // 512 WGs x 4 waves = 2048 persistent waves, 4 units each (8192 units)
  jpeg_fused<<<dim3(512), dim3(256), 0, stream>>>(in, quant, out);
}

// Round 10
// 78.400 us; speedup vs baseline: 1.0039x; 1.0039x over previous
//
#include <hip/hip_runtime.h>
#include <cmath>

// JPEG layer, fully fused, persistent-wave software-prefetch pipeline.
// 2048 waves; each handles 4 "units" (unit = 4 horizontal 16x16 tiles) at the
// same (trow,tcq) across images {i, i+8, i+16, i+24} (constant ptr stride).
// Per iteration: consume prefetched pixel registers -> issue next unit's 12
// float4 loads -> sched_barrier pins them -> ~2500-instr codec block hides
// the latency. Lane (g=lane>>3, p=lane&7) owns row p of block-slot g.
// Butterfly 8-pt DCT/IDCT in-lane + DPP in-register 8x8 transposes.
// Quantizer round() decisions are f64-faithful via rare cold rescue.

#define LEVELD 0.5019607843137255
#define LEVELF 0.5019607843137255f
#define BAND   5.0e-5f

#define CA  0.35355339059327373f
#define CB0 0.49039264020161522f
#define CB1 0.41573480615127262f
#define CB2 0.27778511650980114f
#define CB3 0.09754516100806413f
#define CC0 0.46193976625564337f
#define CC1 0.19134171618254489f

__device__ const double DMATD[64] = {
  0.3535533905932738,  0.3535533905932738,  0.3535533905932738,  0.3535533905932738,
  0.3535533905932738,  0.3535533905932738,  0.3535533905932738,  0.3535533905932738,
  0.4903926402016152,  0.4157348061512726,  0.2777851165098011,  0.0975451610080641,
 -0.0975451610080641, -0.2777851165098011, -0.4157348061512726, -0.4903926402016152,
  0.4619397662556434,  0.1913417161825449, -0.1913417161825449, -0.4619397662556434,
 -0.4619397662556434, -0.1913417161825449,  0.1913417161825449,  0.4619397662556434,
  0.4157348061512726, -0.0975451610080641, -0.4903926402016152, -0.2777851165098011,
  0.2777851165098011,  0.4903926402016152,  0.0975451610080641, -0.4157348061512726,
  0.3535533905932738, -0.3535533905932738, -0.3535533905932738,  0.3535533905932738,
  0.3535533905932738, -0.3535533905932738, -0.3535533905932738,  0.3535533905932738,
  0.2777851165098011, -0.4903926402016152,  0.0975451610080641,  0.4157348061512726,
 -0.4157348061512726, -0.0975451610080641,  0.4903926402016152, -0.2777851165098011,
  0.1913417161825449, -0.4619397662556434,  0.4619397662556434, -0.1913417161825449,
 -0.1913417161825449,  0.4619397662556434, -0.4619397662556434,  0.1913417161825449,
  0.0975451610080641, -0.2777851165098011,  0.4157348061512726, -0.4903926402016152,
  0.4903926402016152, -0.4157348061512726,  0.2777851165098011, -0.0975451610080641
};

// ---- DPP cross-lane helpers (VALU only) ----
__device__ __forceinline__ float dpp_xor1(float x) {  // quad_perm(1,0,3,2)
  return __int_as_float(__builtin_amdgcn_mov_dpp(__float_as_int(x), 0xB1, 0xF, 0xF, true));
}
__device__ __forceinline__ float dpp_xor2(float x) {  // quad_perm(2,3,0,1)
  return __int_as_float(__builtin_amdgcn_mov_dpp(__float_as_int(x), 0x4E, 0xF, 0xF, true));
}
__device__ __forceinline__ float dpp_xor4(float x) {  // half_mirror o quad_mirror
  int t = __builtin_amdgcn_mov_dpp(__float_as_int(x), 0x141, 0xF, 0xF, true);
  return __int_as_float(__builtin_amdgcn_mov_dpp(t, 0x1B, 0xF, 0xF, true));
}

// in-register 8x8 transpose across the 8 lanes of a group; v[j]@p -> v[p]@j
__device__ __forceinline__ void transpose8(float v[8], int p) {
  { float t[8];
    #pragma unroll
    for (int j = 0; j < 8; ++j) t[j] = dpp_xor1(v[j ^ 1]);
    const bool lb = (p & 1) != 0;
    #pragma unroll
    for (int j = 0; j < 8; ++j) v[j] = (lb == ((j & 1) != 0)) ? v[j] : t[j];
  }
  { float t[8];
    #pragma unroll
    for (int j = 0; j < 8; ++j) t[j] = dpp_xor2(v[j ^ 2]);
    const bool lb = (p & 2) != 0;
    #pragma unroll
    for (int j = 0; j < 8; ++j) v[j] = (lb == ((j & 2) != 0)) ? v[j] : t[j];
  }
  { float t[8];
    #pragma unroll
    for (int j = 0; j < 8; ++j) t[j] = dpp_xor4(v[j ^ 4]);
    const bool lb = (p & 4) != 0;
    #pragma unroll
    for (int j = 0; j < 8; ++j) v[j] = (lb == ((j & 4) != 0)) ? v[j] : t[j];
  }
}

// forward 8-pt DCT (y = D x), butterflied
__device__ __forceinline__ void fdct8b(float x[8]) {
  const float s0 = x[0] + x[7], s1 = x[1] + x[6], s2 = x[2] + x[5], s3 = x[3] + x[4];
  const float d0 = x[0] - x[7], d1 = x[1] - x[6], d2 = x[2] - x[5], d3 = x[3] - x[4];
  const float t0 = s0 + s3, t1 = s1 + s2, t2 = s0 - s3, t3 = s1 - s2;
  x[0] = CA * (t0 + t1);
  x[4] = CA * (t0 - t1);
  x[2] = fmaf(CC0, t2,  CC1 * t3);
  x[6] = fmaf(CC1, t2, -CC0 * t3);
  x[1] = fmaf(CB0, d0, fmaf( CB1, d1, fmaf( CB2, d2,  CB3 * d3)));
  x[3] = fmaf(CB1, d0, fmaf(-CB3, d1, fmaf(-CB0, d2, -CB2 * d3)));
  x[5] = fmaf(CB2, d0, fmaf(-CB0, d1, fmaf( CB3, d2,  CB1 * d3)));
  x[7] = fmaf(CB3, d0, fmaf(-CB2, d1, fmaf( CB1, d2, -CB0 * d3)));
}
// inverse 8-pt DCT (o = D^T y), butterflied
__device__ __forceinline__ void idct8b(float y[8]) {
  const float pe = CA * (y[0] + y[4]), qe = CA * (y[0] - y[4]);
  const float re = fmaf(CC0, y[2],  CC1 * y[6]);
  const float se = fmaf(CC1, y[2], -CC0 * y[6]);
  const float E0 = pe + re, E3 = pe - re, E1 = qe + se, E2 = qe - se;
  const float O0 = fmaf(CB0, y[1], fmaf( CB1, y[3], fmaf( CB2, y[5],  CB3 * y[7])));
  const float O1 = fmaf(CB1, y[1], fmaf(-CB3, y[3], fmaf(-CB0, y[5], -CB2 * y[7])));
  const float O2 = fmaf(CB2, y[1], fmaf(-CB0, y[3], fmaf( CB3, y[5],  CB1 * y[7])));
  const float O3 = fmaf(CB3, y[1], fmaf(-CB2, y[3], fmaf( CB1, y[5], -CB0 * y[7])));
  y[0] = E0 + O0; y[7] = E0 - O0;
  y[1] = E1 + O1; y[6] = E1 - O1;
  y[2] = E2 + O2; y[5] = E2 - O2;
  y[3] = E3 + O3; y[4] = E3 - O3;
}

// f64 recompute of dequantized coefficient (i,j). mode 0 = Y (base = 8x8
// block base), mode 1 = Cb, mode 2 = Cr (base = 16x16 tile base). Cold.
__device__ __attribute__((noinline)) float rescue_coef(
    const float* __restrict__ quant, const float* __restrict__ base,
    int mode, int i, int j)
{
  double acc = 0.0;
  if (mode == 0) {
    #pragma unroll 1
    for (int k = 0; k < 8; ++k) {
      double e = 0.0;
      #pragma unroll
      for (int l = 0; l < 8; ++l) {
        const size_t off = (size_t)k * 512 + l;
        const double rr = (double)base[off];
        const double gg = (double)base[262144 + off];
        const double bb = (double)base[524288 + off];
        double y = 0.299 * rr + 0.587 * gg + 0.114 * bb;
        y = fmin(fmax(y, 0.0), 1.0) - LEVELD;
        e += y * DMATD[j * 8 + l];
      }
      acc += DMATD[i * 8 + k] * e;
    }
  } else {
    const double c0 = (mode == 1) ? -0.168735892 : 0.5;
    const double c1 = (mode == 1) ? -0.331264108 : -0.418687589;
    const double c2 = (mode == 1) ?  0.5         : -0.081312411;
    #pragma unroll 1
    for (int k = 0; k < 8; ++k) {
      double e = 0.0;
      #pragma unroll 1
      for (int l = 0; l < 8; ++l) {
        double m = 0.0;
        #pragma unroll
        for (int dr = 0; dr < 2; ++dr)
          #pragma unroll
          for (int dc = 0; dc < 2; ++dc) {
            const size_t off = (size_t)(2 * k + dr) * 512 + (2 * l + dc);
            const double rr = (double)base[off];
            const double gg = (double)base[262144 + off];
            const double bb = (double)base[524288 + off];
            const double v = c0 * rr + c1 * gg + c2 * bb;
            m += fmin(fmax(v + LEVELD, 0.0), 1.0) - LEVELD;
          }
        e += (0.25 * m) * DMATD[j * 8 + l];
      }
      acc += DMATD[i * 8 + k] * e;
    }
  }
  const double qd = rint((double)quant[i * 8 + j] * 255.0) * (1.0 / 255.0);
  return (float)(rint(acc / qd) * qd);
}

// per-block codec: DCT -> quant(round; deferred f64 rescue) -> IDCT, in place
__device__ __forceinline__ void codec8(float x[8], const float qv[8], const float rq[8],
                                       int p, int mode, const float* __restrict__ base,
                                       const float* __restrict__ quant)
{
  fdct8b(x); transpose8(x, p); fdct8b(x);
  unsigned bad = 0u;
  #pragma unroll
  for (int i = 0; i < 8; ++i) {
    const float tt = x[i] * rq[i];
    const float rt = rintf(tt);
    if (fabsf(tt - rt) > 0.5f - BAND) bad |= (1u << i);
    x[i] = rt * qv[i];
  }
  if (__builtin_expect(bad != 0u, 0)) {     // cold, branched-over patch
    do {
      const int i = __builtin_ctz(bad);
      bad &= bad - 1u;
      const float fix = rescue_coef(quant, base, mode, i, p);
      #pragma unroll
      for (int k = 0; k < 8; ++k) x[k] = (k == i) ? fix : x[k];
    } while (bad != 0u);
  }
  idct8b(x); transpose8(x, p); idct8b(x);
}

// issue the 12 float4 pixel loads of one unit into P[12]
__device__ __forceinline__ void load_unit(const float* __restrict__ tb,
                                          size_t lanerow, float4 P[12])
{
  #pragma unroll
  for (int h = 0; h < 2; ++h) {
    const float* pb = tb + lanerow + h * 32;   // tY = 2h+tx
    P[6 * h + 0] = *(const float4*)(pb);
    P[6 * h + 1] = *(const float4*)(pb + 4);
    P[6 * h + 2] = *(const float4*)(pb + 262144);
    P[6 * h + 3] = *(const float4*)(pb + 262148);
    P[6 * h + 4] = *(const float4*)(pb + 524288);
    P[6 * h + 5] = *(const float4*)(pb + 524292);
  }
}

// color + chroma-mean staging for one Y round (data already in registers)
__device__ __forceinline__ void color_stage(
    const float4* __restrict__ L6, int tY, int qr, int qc, int p,
    float4* __restrict__ CHW, float rout[8])
{
  const float RL[8] = {L6[0].x, L6[0].y, L6[0].z, L6[0].w, L6[1].x, L6[1].y, L6[1].z, L6[1].w};
  const float GL[8] = {L6[2].x, L6[2].y, L6[2].z, L6[2].w, L6[3].x, L6[3].y, L6[3].z, L6[3].w};
  const float BL[8] = {L6[4].x, L6[4].y, L6[4].z, L6[4].w, L6[5].x, L6[5].y, L6[5].z, L6[5].w};

  float cbv[8], crv[8];
  #pragma unroll
  for (int l = 0; l < 8; ++l) {
    const float rr = RL[l], gg = GL[l], bb = BL[l];
    const float y  = fmaf(0.114f, bb, fmaf(0.587f, gg, 0.299f * rr));
    const float cb = fmaf(0.5f, bb, fmaf(-0.331264108f, gg, -0.168735892f * rr));
    const float cr = fmaf(-0.081312411f, bb, fmaf(-0.418687589f, gg, 0.5f * rr));
    rout[l] = fminf(fmaxf(y,           0.0f), 1.0f) - LEVELF;
    cbv[l]  = fminf(fmaxf(cb + LEVELF, 0.0f), 1.0f) - LEVELF;
    crv[l]  = fminf(fmaxf(cr + LEVELF, 0.0f), 1.0f) - LEVELF;
  }
  float ch[4];
  #pragma unroll
  for (int j = 0; j < 4; ++j) {
    const float cbh = cbv[2 * j] + cbv[2 * j + 1];
    const float crh = crv[2 * j] + crv[2 * j + 1];
    const float cbs = cbh + dpp_xor1(cbh);
    const float crs = crh + dpp_xor1(crh);
    ch[j] = 0.25f * ((p & 1) ? crs : cbs);   // even lanes: cb, odd: cr
  }
  const int crow = qr * 4 + (p >> 1);
  const int slot = ((((p & 1) * 4 + tY) * 16) + crow * 2 + qc) ^ ((tY << 1) | qr);
  CHW[slot] = make_float4(ch[0], ch[1], ch[2], ch[3]);
}

// upsample chroma from LDS, YCC->RGB, clamp, store one Y round
__device__ __forceinline__ void out_phase(
    float* __restrict__ ob, int tY, int qr, int qc, int p,
    const float4* __restrict__ CHW, const float r[8])
{
  const int crow = qr * 4 + (p >> 1);
  const int swz = (tY << 1) | qr;
  const float4 cb4 = CHW[((tY * 16) + crow * 2 + qc) ^ swz];
  const float4 cr4 = CHW[(((4 + tY) * 16) + crow * 2 + qc) ^ swz];
  const float cba[4] = {cb4.x, cb4.y, cb4.z, cb4.w};
  const float cra[4] = {cr4.x, cr4.y, cr4.z, cr4.w};

  float RR[8], GG[8], BB[8];
  #pragma unroll
  for (int l = 0; l < 8; ++l) {
    const float y2 = r[l] + LEVELF;          // chroma LEVEL offsets cancel
    const float cbb = cba[l >> 1], crr = cra[l >> 1];
    float ro = fmaf(1.402f, crr, y2);
    float go = y2 - 0.344136286f * cbb - 0.714136286f * crr;
    float bo = fmaf(1.772f, cbb, y2);
    RR[l] = fminf(fmaxf(ro, 0.0f), 1.0f);
    GG[l] = fminf(fmaxf(go, 0.0f), 1.0f);
    BB[l] = fminf(fmaxf(bo, 0.0f), 1.0f);
  }
  float* op = ob + (size_t)(qr * 8 + p) * 512 + tY * 16 + qc * 8;
  *(float4*)(op)              = make_float4(RR[0], RR[1], RR[2], RR[3]);
  *(float4*)(op + 4)          = make_float4(RR[4], RR[5], RR[6], RR[7]);
  *(float4*)(op + 262144)     = make_float4(GG[0], GG[1], GG[2], GG[3]);
  *(float4*)(op + 262148)     = make_float4(GG[4], GG[5], GG[6], GG[7]);
  *(float4*)(op + 524288)     = make_float4(BB[0], BB[1], BB[2], BB[3]);
  *(float4*)(op + 524292)     = make_float4(BB[4], BB[5], BB[6], BB[7]);
}

#define UNIT_STRIDE 6291456   // 8 images * 786432 floats

__global__ __launch_bounds__(256, 2) void jpeg_fused(
    const float* __restrict__ in, const float* __restrict__ quant,
    float* __restrict__ out)
{
  __shared__ float4 CH[4][128];   // per wave: 8 chroma blocks (swizzled), 2 KiB

  const int wv   = threadIdx.x >> 6;
  const int lane = threadIdx.x & 63;
  const int g = lane >> 3, p = lane & 7;
  const int tx = g >> 2, qr = (g >> 1) & 1, qc = g & 1;

  // wave 0..2047: images {img0, img0+8, img0+16, img0+24} at (trow, tcq)
  const int wave_id = blockIdx.x * 4 + wv;
  const int img0 = wave_id >> 8;
  const int trow = (wave_id >> 3) & 31;
  const int tcq  = wave_id & 7;
  const size_t base0 = (size_t)img0 * 786432 + (size_t)trow * 8192 + (size_t)tcq * 64;
  float4* CHW = &CH[wv][0];

  // per-lane offset of Y-row within a unit (tile-half h adds +32)
  const size_t lanerow = (size_t)(qr * 8 + p) * 512 + tx * 16 + qc * 8;

  // quantizer column p in f32: rintf(q*255) exact for q*255 in [40,50];
  // <=1-ulp dequant diff vs f64, arbitrated by the f64 rescue anyway
  float qv[8], rq[8];
  #pragma unroll
  for (int i = 0; i < 8; ++i) {
    qv[i] = rintf(quant[i * 8 + p] * 255.0f) * (1.0f / 255.0f);
    rq[i] = 1.0f / qv[i];
  }

  float4 P[12];
  load_unit(in + base0, lanerow, P);          // prologue prefetch (unit 0)

  #pragma unroll 1
  for (int k = 0; k < 4; ++k) {
    const float* tb_cur = in + base0 + (size_t)k * UNIT_STRIDE;
    float* ob = out + base0 + (size_t)k * UNIT_STRIDE;

    // consume prefetched registers (the only vmcnt wait per iteration)
    float rA[8], rB[8];
    color_stage(&P[0], 0 + tx, qr, qc, p, CHW, rA);
    color_stage(&P[6], 2 + tx, qr, qc, p, CHW, rB);
    __builtin_amdgcn_wave_barrier();

    // issue next unit's loads now; pin them above the codec block
    if (k < 3) load_unit(tb_cur + UNIT_STRIDE, lanerow, P);
    __builtin_amdgcn_sched_barrier(0);

    // ---- Y codecs (call-free fast path) ----
    const float* blkA = tb_cur + (size_t)qr * 4096 + (0 + tx) * 16 + qc * 8;
    const float* blkB = tb_cur + (size_t)qr * 4096 + (2 + tx) * 16 + qc * 8;
    codec8(rA, qv, rq, p, 0, blkA, quant);
    codec8(rB, qv, rq, p, 0, blkB, quant);

    // ---- chroma codec: 8 blocks (g>>2: 0=Cb,1=Cr; g&3: unit tile) ----
    {
      const int cpar = g >> 2, ct = g & 3;
      const int pre  = (cpar * 4 + ct) * 16 + p * 2;
      const int swz  = (ct << 1) | (p >> 2);
      const int sl = pre ^ swz, sh = (pre + 1) ^ swz;
      const float4 a = CHW[sl];
      const float4 b = CHW[sh];
      float xc[8] = {a.x, a.y, a.z, a.w, b.x, b.y, b.z, b.w};
      codec8(xc, qv, rq, p, 1 + cpar, tb_cur + ct * 16, quant);
      CHW[sl] = make_float4(xc[0], xc[1], xc[2], xc[3]);
      CHW[sh] = make_float4(xc[4], xc[5], xc[6], xc[7]);
    }
    __builtin_amdgcn_wave_barrier();

    // ---- output both rounds ----
    out_phase(ob, 0 + tx, qr, qc, p, CHW, rA);
    out_phase(ob, 2 + tx, qr, qc, p, CHW, rB);
    __builtin_amdgcn_wave_barrier();
  }
}

extern "C" void kernel_launch(void* const* d_in, const int* in_sizes, int n_in,
                              void* d_out, int out_size, void* d_ws, size_t ws_size,
                              hipStream_t stream) {
  const float* in    = (const float*)d_in[0];
  const float* quant = (const float*)d_in[1];  // only quantize[0] (64 floats) used
  float* out = (float*)d_out;

  // 512 WGs x 4 waves = 2048 persistent waves, 4 units each (8192 units)
  jpeg_fused<<<dim3(512), dim3(256), 0, stream>>>(in, quant, out);
}

// Round 11
// 73.073 us; speedup vs baseline: 1.0771x; 1.0729x over previous
//
#include <hip/hip_runtime.h>
#include <cmath>

// JPEG layer, fully fused, BAND design: one 256-thread WG owns a 16x256
// pixel strip (half of one tile-row). All global loads/stores are perfectly
// coalesced (lane i <-> consecutive float4, 1KB per wave instruction).
// LDS mediates pixel-major <-> block-major. Codec = butterfly 8-pt DCT/IDCT
// in-lane + DPP in-register 8x8 transpose (unchanged from R6), quantizer
// round() decisions f64-faithful via rare cold rescue from global pixels.
// Rounds: A = Y blocks 0..31, B = Y blocks 32..63, C = 16 Cb + 16 Cr; all
// 8 lane-groups of every wave are full in every round.

#define LEVELD 0.5019607843137255
#define LEVELF 0.5019607843137255f
#define BAND   5.0e-5f

#define CA  0.35355339059327373f
#define CB0 0.49039264020161522f
#define CB1 0.41573480615127262f
#define CB2 0.27778511650980114f
#define CB3 0.09754516100806413f
#define CC0 0.46193976625564337f
#define CC1 0.19134171618254489f

__device__ const double DMATD[64] = {
  0.3535533905932738,  0.3535533905932738,  0.3535533905932738,  0.3535533905932738,
  0.3535533905932738,  0.3535533905932738,  0.3535533905932738,  0.3535533905932738,
  0.4903926402016152,  0.4157348061512726,  0.2777851165098011,  0.0975451610080641,
 -0.0975451610080641, -0.2777851165098011, -0.4157348061512726, -0.4903926402016152,
  0.4619397662556434,  0.1913417161825449, -0.1913417161825449, -0.4619397662556434,
 -0.4619397662556434, -0.1913417161825449,  0.1913417161825449,  0.4619397662556434,
  0.4157348061512726, -0.0975451610080641, -0.4903926402016152, -0.2777851165098011,
  0.2777851165098011,  0.4903926402016152,  0.0975451610080641, -0.4157348061512726,
  0.3535533905932738, -0.3535533905932738, -0.3535533905932738,  0.3535533905932738,
  0.3535533905932738, -0.3535533905932738, -0.3535533905932738,  0.3535533905932738,
  0.2777851165098011, -0.4903926402016152,  0.0975451610080641,  0.4157348061512726,
 -0.4157348061512726, -0.0975451610080641,  0.4903926402016152, -0.2777851165098011,
  0.1913417161825449, -0.4619397662556434,  0.4619397662556434, -0.1913417161825449,
 -0.1913417161825449,  0.4619397662556434, -0.4619397662556434,  0.1913417161825449,
  0.0975451610080641, -0.2777851165098011,  0.4157348061512726, -0.4903926402016152,
  0.4903926402016152, -0.4157348061512726,  0.2777851165098011, -0.0975451610080641
};

// ---- DPP cross-lane helpers (VALU only) ----
__device__ __forceinline__ float dpp_xor1(float x) {  // quad_perm(1,0,3,2)
  return __int_as_float(__builtin_amdgcn_mov_dpp(__float_as_int(x), 0xB1, 0xF, 0xF, true));
}
__device__ __forceinline__ float dpp_xor2(float x) {  // quad_perm(2,3,0,1)
  return __int_as_float(__builtin_amdgcn_mov_dpp(__float_as_int(x), 0x4E, 0xF, 0xF, true));
}
__device__ __forceinline__ float dpp_xor4(float x) {  // half_mirror o quad_mirror
  int t = __builtin_amdgcn_mov_dpp(__float_as_int(x), 0x141, 0xF, 0xF, true);
  return __int_as_float(__builtin_amdgcn_mov_dpp(t, 0x1B, 0xF, 0xF, true));
}

// in-register 8x8 transpose across the 8 lanes of a group; v[j]@p -> v[p]@j
__device__ __forceinline__ void transpose8(float v[8], int p) {
  { float t[8];
    #pragma unroll
    for (int j = 0; j < 8; ++j) t[j] = dpp_xor1(v[j ^ 1]);
    const bool lb = (p & 1) != 0;
    #pragma unroll
    for (int j = 0; j < 8; ++j) v[j] = (lb == ((j & 1) != 0)) ? v[j] : t[j];
  }
  { float t[8];
    #pragma unroll
    for (int j = 0; j < 8; ++j) t[j] = dpp_xor2(v[j ^ 2]);
    const bool lb = (p & 2) != 0;
    #pragma unroll
    for (int j = 0; j < 8; ++j) v[j] = (lb == ((j & 2) != 0)) ? v[j] : t[j];
  }
  { float t[8];
    #pragma unroll
    for (int j = 0; j < 8; ++j) t[j] = dpp_xor4(v[j ^ 4]);
    const bool lb = (p & 4) != 0;
    #pragma unroll
    for (int j = 0; j < 8; ++j) v[j] = (lb == ((j & 4) != 0)) ? v[j] : t[j];
  }
}

// forward 8-pt DCT (y = D x), butterflied
__device__ __forceinline__ void fdct8b(float x[8]) {
  const float s0 = x[0] + x[7], s1 = x[1] + x[6], s2 = x[2] + x[5], s3 = x[3] + x[4];
  const float d0 = x[0] - x[7], d1 = x[1] - x[6], d2 = x[2] - x[5], d3 = x[3] - x[4];
  const float t0 = s0 + s3, t1 = s1 + s2, t2 = s0 - s3, t3 = s1 - s2;
  x[0] = CA * (t0 + t1);
  x[4] = CA * (t0 - t1);
  x[2] = fmaf(CC0, t2,  CC1 * t3);
  x[6] = fmaf(CC1, t2, -CC0 * t3);
  x[1] = fmaf(CB0, d0, fmaf( CB1, d1, fmaf( CB2, d2,  CB3 * d3)));
  x[3] = fmaf(CB1, d0, fmaf(-CB3, d1, fmaf(-CB0, d2, -CB2 * d3)));
  x[5] = fmaf(CB2, d0, fmaf(-CB0, d1, fmaf( CB3, d2,  CB1 * d3)));
  x[7] = fmaf(CB3, d0, fmaf(-CB2, d1, fmaf( CB1, d2, -CB0 * d3)));
}
// inverse 8-pt DCT (o = D^T y), butterflied
__device__ __forceinline__ void idct8b(float y[8]) {
  const float pe = CA * (y[0] + y[4]), qe = CA * (y[0] - y[4]);
  const float re = fmaf(CC0, y[2],  CC1 * y[6]);
  const float se = fmaf(CC1, y[2], -CC0 * y[6]);
  const float E0 = pe + re, E3 = pe - re, E1 = qe + se, E2 = qe - se;
  const float O0 = fmaf(CB0, y[1], fmaf( CB1, y[3], fmaf( CB2, y[5],  CB3 * y[7])));
  const float O1 = fmaf(CB1, y[1], fmaf(-CB3, y[3], fmaf(-CB0, y[5], -CB2 * y[7])));
  const float O2 = fmaf(CB2, y[1], fmaf(-CB0, y[3], fmaf( CB3, y[5],  CB1 * y[7])));
  const float O3 = fmaf(CB3, y[1], fmaf(-CB2, y[3], fmaf( CB1, y[5], -CB0 * y[7])));
  y[0] = E0 + O0; y[7] = E0 - O0;
  y[1] = E1 + O1; y[6] = E1 - O1;
  y[2] = E2 + O2; y[5] = E2 - O2;
  y[3] = E3 + O3; y[4] = E3 - O3;
}

// f64 recompute of rounded quotient for coefficient (i,j). mode 0 = Y
// (base = 8x8 block base), mode 1 = Cb, mode 2 = Cr (base = 16x16 tile
// base). Cold path.
__device__ __attribute__((noinline)) float rescue_coef(
    const float* __restrict__ quant, const float* __restrict__ base,
    int mode, int i, int j)
{
  double acc = 0.0;
  if (mode == 0) {
    #pragma unroll 1
    for (int k = 0; k < 8; ++k) {
      double e = 0.0;
      #pragma unroll
      for (int l = 0; l < 8; ++l) {
        const size_t off = (size_t)k * 512 + l;
        const double rr = (double)base[off];
        const double gg = (double)base[262144 + off];
        const double bb = (double)base[524288 + off];
        double y = 0.299 * rr + 0.587 * gg + 0.114 * bb;
        y = fmin(fmax(y, 0.0), 1.0) - LEVELD;
        e += y * DMATD[j * 8 + l];
      }
      acc += DMATD[i * 8 + k] * e;
    }
  } else {
    const double c0 = (mode == 1) ? -0.168735892 : 0.5;
    const double c1 = (mode == 1) ? -0.331264108 : -0.418687589;
    const double c2 = (mode == 1) ?  0.5         : -0.081312411;
    #pragma unroll 1
    for (int k = 0; k < 8; ++k) {
      double e = 0.0;
      #pragma unroll 1
      for (int l = 0; l < 8; ++l) {
        double m = 0.0;
        #pragma unroll
        for (int dr = 0; dr < 2; ++dr)
          #pragma unroll
          for (int dc = 0; dc < 2; ++dc) {
            const size_t off = (size_t)(2 * k + dr) * 512 + (2 * l + dc);
            const double rr = (double)base[off];
            const double gg = (double)base[262144 + off];
            const double bb = (double)base[524288 + off];
            const double v = c0 * rr + c1 * gg + c2 * bb;
            m += fmin(fmax(v + LEVELD, 0.0), 1.0) - LEVELD;
          }
        e += (0.25 * m) * DMATD[j * 8 + l];
      }
      acc += DMATD[i * 8 + k] * e;
    }
  }
  const double qd = rint((double)quant[i * 8 + j] * 255.0) * (1.0 / 255.0);
  return (float)(rint(acc / qd) * qd);
}

// per-block codec: DCT -> quant(round; deferred f64 rescue) -> IDCT, in place
__device__ __forceinline__ void codec8(float x[8], const float qv[8], const float rq[8],
                                       int p, int mode, const float* __restrict__ base,
                                       const float* __restrict__ quant)
{
  fdct8b(x); transpose8(x, p); fdct8b(x);
  unsigned bad = 0u;
  #pragma unroll
  for (int i = 0; i < 8; ++i) {
    const float tt = x[i] * rq[i];
    const float rt = rintf(tt);
    if (fabsf(tt - rt) > 0.5f - BAND) bad |= (1u << i);
    x[i] = rt * qv[i];
  }
  if (__builtin_expect(bad != 0u, 0)) {     // cold, branched-over patch
    do {
      const int i = __builtin_ctz(bad);
      bad &= bad - 1u;
      const float fix = rescue_coef(quant, base, mode, i, p);
      #pragma unroll
      for (int k = 0; k < 8; ++k) x[k] = (k == i) ? fix : x[k];
    } while (bad != 0u);
  }
  idct8b(x); transpose8(x, p); idct8b(x);
}

#define YSTRIDE 260   // 256 + 4 pad -> conflict-free b128 column spread
#define CSTRIDE 132   // 128 + 4 pad

__global__ __launch_bounds__(256, 6) void jpeg_band(
    const float* __restrict__ in, const float* __restrict__ quant,
    float* __restrict__ out)
{
  __shared__ float Ylds[16 * YSTRIDE];       // 16.6 KB
  __shared__ float Clds[2][8 * CSTRIDE];     // 2 x 4.2 KB

  const int t    = threadIdx.x;
  const int wave = t >> 6;
  const int lane = t & 63;
  const int g = lane >> 3, p = lane & 7;

  const int band = blockIdx.x;               // 2048 = 32 img x 32 trow x 2
  const int img  = band >> 6;
  const int trow = (band >> 1) & 31;
  const int half = band & 1;
  const size_t base = (size_t)img * 786432 + (size_t)trow * 8192 + (size_t)half * 256;

  // quantizer column p (f32 exact: q*255 in [40,50]); f64 rescue arbitrates
  float qv[8], rq[8];
  #pragma unroll
  for (int i = 0; i < 8; ++i) {
    qv[i] = rintf(quant[i * 8 + p] * 255.0f) * (1.0f / 255.0f);
    rq[i] = 1.0f / qv[i];
  }

  // ================= color phase: coalesced load, YCC, stage =================
  {
    const int row = t >> 4;                  // 0..15
    const int c0  = (t & 15) * 16;           // 16 px per thread
    const float* pr = in + base + (size_t)row * 512 + c0;

    float4 R[4], G[4], B[4];
    #pragma unroll
    for (int i = 0; i < 4; ++i) R[i] = *(const float4*)(pr + 4 * i);
    #pragma unroll
    for (int i = 0; i < 4; ++i) G[i] = *(const float4*)(pr + 262144 + 4 * i);
    #pragma unroll
    for (int i = 0; i < 4; ++i) B[i] = *(const float4*)(pr + 524288 + 4 * i);

    float yv[16], cbv[16], crv[16];
    #pragma unroll
    for (int i = 0; i < 16; ++i) {
      const float rr = ((const float*)R)[i];
      const float gg = ((const float*)G)[i];
      const float bb = ((const float*)B)[i];
      const float y  = fmaf(0.114f, bb, fmaf(0.587f, gg, 0.299f * rr));
      const float cb = fmaf(0.5f, bb, fmaf(-0.331264108f, gg, -0.168735892f * rr));
      const float cr = fmaf(-0.081312411f, bb, fmaf(-0.418687589f, gg, 0.5f * rr));
      yv[i]  = fminf(fmaxf(y,           0.0f), 1.0f) - LEVELF;
      cbv[i] = fminf(fmaxf(cb + LEVELF, 0.0f), 1.0f) - LEVELF;
      crv[i] = fminf(fmaxf(cr + LEVELF, 0.0f), 1.0f) - LEVELF;
    }

    float* yw = &Ylds[row * YSTRIDE + c0];
    #pragma unroll
    for (int i = 0; i < 4; ++i)
      *(float4*)(yw + 4 * i) = make_float4(yv[4*i], yv[4*i+1], yv[4*i+2], yv[4*i+3]);

    // 2x2 chroma mean: horizontal in-lane, vertical via shfl_xor(16) (row^1)
    float cbh[8], crh[8];
    #pragma unroll
    for (int j = 0; j < 8; ++j) {
      cbh[j] = cbv[2*j] + cbv[2*j+1];
      crh[j] = crv[2*j] + crv[2*j+1];
    }
    #pragma unroll
    for (int j = 0; j < 8; ++j) {
      cbh[j] = 0.25f * (cbh[j] + __shfl_xor(cbh[j], 16));
      crh[j] = 0.25f * (crh[j] + __shfl_xor(crh[j], 16));
    }
    if ((row & 1) == 0) {
      float* cw0 = &Clds[0][(row >> 1) * CSTRIDE + (c0 >> 1)];
      float* cw1 = &Clds[1][(row >> 1) * CSTRIDE + (c0 >> 1)];
      *(float4*)(cw0)     = make_float4(cbh[0], cbh[1], cbh[2], cbh[3]);
      *(float4*)(cw0 + 4) = make_float4(cbh[4], cbh[5], cbh[6], cbh[7]);
      *(float4*)(cw1)     = make_float4(crh[0], crh[1], crh[2], crh[3]);
      *(float4*)(cw1 + 4) = make_float4(crh[4], crh[5], crh[6], crh[7]);
    }
  }
  __syncthreads();

  // ================= block codec rounds (all lanes full) =================
  // Round A: Y blocks 0..31 (brow 0); Round B: 32..63 (brow 1)
  #pragma unroll
  for (int r = 0; r < 2; ++r) {
    const int id   = r * 32 + wave * 8 + g;
    const int brow = id >> 5, bcol = id & 31;
    float* yr = &Ylds[(brow * 8 + p) * YSTRIDE + bcol * 8];
    float x[8];
    { const float4 a = *(const float4*)(yr);
      const float4 b = *(const float4*)(yr + 4);
      x[0]=a.x; x[1]=a.y; x[2]=a.z; x[3]=a.w; x[4]=b.x; x[5]=b.y; x[6]=b.z; x[7]=b.w; }
    const float* gbase = in + base + (size_t)(brow * 8) * 512 + bcol * 8;
    codec8(x, qv, rq, p, 0, gbase, quant);
    *(float4*)(yr)     = make_float4(x[0], x[1], x[2], x[3]);
    *(float4*)(yr + 4) = make_float4(x[4], x[5], x[6], x[7]);
  }
  // Round C: 16 Cb + 16 Cr
  {
    const int cid = wave * 8 + g;
    const int ch  = cid >> 4, bc = cid & 15;
    float* cr_ = &Clds[ch][p * CSTRIDE + bc * 8];
    float x[8];
    { const float4 a = *(const float4*)(cr_);
      const float4 b = *(const float4*)(cr_ + 4);
      x[0]=a.x; x[1]=a.y; x[2]=a.z; x[3]=a.w; x[4]=b.x; x[5]=b.y; x[6]=b.z; x[7]=b.w; }
    const float* gbase = in + base + bc * 16;
    codec8(x, qv, rq, p, 1 + ch, gbase, quant);
    *(float4*)(cr_)     = make_float4(x[0], x[1], x[2], x[3]);
    *(float4*)(cr_ + 4) = make_float4(x[4], x[5], x[6], x[7]);
  }
  __syncthreads();

  // ================= output phase: upsample, YCC->RGB, coalesced store =====
  {
    const int row = t >> 4;
    const int c0  = (t & 15) * 16;
    const float* yr = &Ylds[row * YSTRIDE + c0];
    const float* cb8 = &Clds[0][(row >> 1) * CSTRIDE + (c0 >> 1)];
    const float* cr8 = &Clds[1][(row >> 1) * CSTRIDE + (c0 >> 1)];

    float RR[16], GG[16], BB[16];
    #pragma unroll
    for (int i = 0; i < 16; ++i) {
      const float y2  = yr[i] + LEVELF;       // chroma LEVEL offsets cancel
      const float cbb = cb8[i >> 1];
      const float crr = cr8[i >> 1];
      float ro = fmaf(1.402f, crr, y2);
      float go = y2 - 0.344136286f * cbb - 0.714136286f * crr;
      float bo = fmaf(1.772f, cbb, y2);
      RR[i] = fminf(fmaxf(ro, 0.0f), 1.0f);
      GG[i] = fminf(fmaxf(go, 0.0f), 1.0f);
      BB[i] = fminf(fmaxf(bo, 0.0f), 1.0f);
    }
    float* po = out + base + (size_t)row * 512 + c0;
    #pragma unroll
    for (int i = 0; i < 4; ++i)
      *(float4*)(po + 4 * i)          = make_float4(RR[4*i], RR[4*i+1], RR[4*i+2], RR[4*i+3]);
    #pragma unroll
    for (int i = 0; i < 4; ++i)
      *(float4*)(po + 262144 + 4 * i) = make_float4(GG[4*i], GG[4*i+1], GG[4*i+2], GG[4*i+3]);
    #pragma unroll
    for (int i = 0; i < 4; ++i)
      *(float4*)(po + 524288 + 4 * i) = make_float4(BB[4*i], BB[4*i+1], BB[4*i+2], BB[4*i+3]);
  }
}

extern "C" void kernel_launch(void* const* d_in, const int* in_sizes, int n_in,
                              void* d_out, int out_size, void* d_ws, size_t ws_size,
                              hipStream_t stream) {
  const float* in    = (const float*)d_in[0];
  const float* quant = (const float*)d_in[1];  // only quantize[0] (64 floats) used
  float* out = (float*)d_out;

  // 2048 WGs: 32 images x 32 tile-rows x 2 half-bands (16x256 px each)
  jpeg_band<<<dim3(2048), dim3(256), 0, stream>>>(in, quant, out);
}